// Round 1
// 25751.199 us; speedup vs baseline: 3.4064x; 3.4064x over previous
//
#include <hip/hip_runtime.h>
#include <cstdint>
#include <cstddef>

#define DEV static __device__ __forceinline__

DEV float wredf(float v) {
  v += __shfl_xor(v, 32, 64); v += __shfl_xor(v, 16, 64);
  v += __shfl_xor(v, 8, 64);  v += __shfl_xor(v, 4, 64);
  v += __shfl_xor(v, 2, 64);  v += __shfl_xor(v, 1, 64);
  return v;
}

DEV void ld4(float* d, const float* p) {
  float4 t = *(const float4*)p;
  d[0] = t.x; d[1] = t.y; d[2] = t.z; d[3] = t.w;
}
DEV void st4(float* p, const float* s) {
  *(float4*)p = make_float4(s[0], s[1], s[2], s[3]);
}

// ---- embed: src = [x,t] @ emb_W + emb_b  (fp32) --------------------------
__global__ __launch_bounds__(256)
void embed_kernel(const float* __restrict__ x, const float* __restrict__ t,
                  const float* __restrict__ W, const float* __restrict__ eb,
                  float* __restrict__ X) {
  const int gid = blockIdx.x * 256 + threadIdx.x;  // R*64
  const int row = gid >> 6, d = (gid & 63) * 8;
  const float xv = x[row], tv = t[row];
  #pragma unroll
  for (int j = 0; j < 8; j++)
    X[(size_t)row * 512 + d + j] =
        xv * W[d + j] + tv * W[512 + d + j] + eb[d + j];
}

// ---- layernorm row=512, fp32 -> fp32, one wave per row -------------------
__global__ __launch_bounds__(256)
void ln_kernel(const float* __restrict__ X, const float* __restrict__ w,
               const float* __restrict__ bb, float* __restrict__ out) {
  const int row = blockIdx.x * 4 + (threadIdx.x >> 6);
  const int lane = threadIdx.x & 63;
  const float* xp = X + (size_t)row * 512 + lane * 8;
  float4 a0 = *(const float4*)xp;
  float4 a1 = *(const float4*)(xp + 4);
  float v[8] = {a0.x, a0.y, a0.z, a0.w, a1.x, a1.y, a1.z, a1.w};
  float s = 0.f, sq = 0.f;
  #pragma unroll
  for (int j = 0; j < 8; j++) { s += v[j]; sq += v[j] * v[j]; }
  s = wredf(s); sq = wredf(sq);
  const float mean = s * (1.f / 512.f);
  const float var = fmaxf(sq * (1.f / 512.f) - mean * mean, 0.f);
  const float inv = rsqrtf(var + 1e-5f);
  const float* wp = w + lane * 8;
  const float* bp = bb + lane * 8;
  float* op = out + (size_t)row * 512 + lane * 8;
  #pragma unroll
  for (int j = 0; j < 8; j++)
    op[j] = (v[j] - mean) * inv * wp[j] + bp[j];
}

// ---- xpos rotation on Q,K inside QKV buffer (row x 2048 fp32) ------------
// Also folds the retention decay: Q *= gamma^s, K *= gamma^-s, so that
// (Q gamma^s)·(K gamma^-m) = (Q·K) * gamma^(s-m). Mask (m>s) done in attn.
__global__ __launch_bounds__(256)
void xpos_kernel(float* __restrict__ QKV) {
  const int gid = blockIdx.x * 256 + threadIdx.x;  // R*256
  const int row = gid >> 8, r = gid & 255;
  const int h = r >> 5, i = r & 31;
  const int s = row & 255;
  const float sv = (2.0f * i + 0.4f * 64.0f) / (1.4f * 64.0f);
  const float sc = powf(sv, (float)s / 512.0f);
  const float isc = 1.0f / sc;
  const float invf = powf(10000.0f, -((float)i) / 32.0f);
  const float ang = (float)s * invf;
  const float sn = sinf(ang), cs = cosf(ang);
  // decay factors
  const float l32 = logf(1.0f / 32.0f), l512 = logf(1.0f / 512.0f);
  const float gamma = 1.0f - expf(l32 + (float)h * (l512 - l32) / 7.0f);
  const float gq = powf(gamma, (float)s);
  const float gk = 1.0f / gq;
  const size_t base = (size_t)row * 2048 + h * 64 + 2 * i;
  const float q0 = QKV[base], q1 = QKV[base + 1];
  const float k0 = QKV[base + 512], k1 = QKV[base + 513];
  const float cq = cs * sc * gq, sq_ = sn * sc * gq;
  const float ck = cs * isc * gk, sk = sn * isc * gk;
  QKV[base]       = q0 * cq - q1 * sq_;
  QKV[base + 1]   = q1 * cq + q0 * sq_;
  QKV[base + 512] = k0 * ck - k1 * sk;
  QKV[base + 513] = k1 * ck + k0 * sk;
}

// ---- tiled causal retention attention (fp32) -----------------------------
// Block: 64 query rows (within one b) x 1 head. Streams K/V tiles of 64 rows
// up to (and including) the diagonal tile; decay already folded into Q/K.
// Phase 1: A[64x64] = Qs^T Ks (GEMM, 4x4 microtile), mask diagonal tile.
// Phase 2: Y[64x128] += A @ V (V streamed from global/L2, 4x8 microtile).
__global__ __launch_bounds__(256)
void attn_tiled(const float* __restrict__ QKV, float* __restrict__ Y) {
  __shared__ float Qs[64][68];   // [e][s]
  __shared__ float Ks[64][68];   // [e][m]
  __shared__ float At[64][68];   // [m][s]
  const int h = blockIdx.y;
  const int r0 = blockIdx.x * 64;       // chunk-local first row
  const int b = r0 >> 8;
  const int s0 = r0 & 255;
  const int st = s0 >> 6;               // diagonal m-tile index
  const int tid = threadIdx.x;
  const int ty = tid >> 4, tx = tid & 15;

  {  // stage Q transposed
    const int rr = tid >> 2, e0 = (tid & 3) * 16;
    const float* qp = QKV + (size_t)(r0 + rr) * 2048 + h * 64 + e0;
    #pragma unroll
    for (int j = 0; j < 16; j++) Qs[e0 + j][rr] = qp[j];
  }

  float acc2[4][8];
  #pragma unroll
  for (int i = 0; i < 4; i++)
    #pragma unroll
    for (int j = 0; j < 8; j++) acc2[i][j] = 0.f;

  for (int mt = 0; mt <= st; mt++) {
    const int m0 = mt * 64;
    {  // stage K tile transposed
      const int rr = tid >> 2, e0 = (tid & 3) * 16;
      const float* kp = QKV + (size_t)(b * 256 + m0 + rr) * 2048 + 512 + h * 64 + e0;
      #pragma unroll
      for (int j = 0; j < 16; j++) Ks[e0 + j][rr] = kp[j];
    }
    __syncthreads();
    // phase 1: A = Q K^T  (rows ty*4.., cols tx*4..)
    float a1[4][4];
    #pragma unroll
    for (int i = 0; i < 4; i++)
      #pragma unroll
      for (int j = 0; j < 4; j++) a1[i][j] = 0.f;
    #pragma unroll 4
    for (int e = 0; e < 64; e++) {
      float qa[4], kb[4];
      ld4(qa, &Qs[e][ty * 4]);
      ld4(kb, &Ks[e][tx * 4]);
      #pragma unroll
      for (int i = 0; i < 4; i++)
        #pragma unroll
        for (int j = 0; j < 4; j++)
          a1[i][j] = fmaf(qa[i], kb[j], a1[i][j]);
    }
    #pragma unroll
    for (int i = 0; i < 4; i++)
      #pragma unroll
      for (int j = 0; j < 4; j++) {
        float v = a1[i][j];
        if (mt == st && (m0 + tx * 4 + j) > (s0 + ty * 4 + i)) v = 0.f;
        At[tx * 4 + j][ty * 4 + i] = v;
      }
    __syncthreads();
    // phase 2: Y += A @ V   (rows ty*4.., v-cols tx*8..)
    const float* vp = QKV + (size_t)(b * 256 + m0) * 2048 + 1024 + h * 128 + tx * 8;
    #pragma unroll 4
    for (int m = 0; m < 64; m++) {
      float av[4], vv[8];
      ld4(av, &At[m][ty * 4]);
      ld4(vv, vp);
      ld4(vv + 4, vp + 4);
      vp += 2048;
      #pragma unroll
      for (int i = 0; i < 4; i++)
        #pragma unroll
        for (int j = 0; j < 8; j++)
          acc2[i][j] = fmaf(av[i], vv[j], acc2[i][j]);
    }
    __syncthreads();
  }
  #pragma unroll
  for (int i = 0; i < 4; i++) {
    float* yp = Y + (size_t)(r0 + ty * 4 + i) * 1024 + h * 128 + tx * 8;
    st4(yp, &acc2[i][0]);
    st4(yp + 4, &acc2[i][4]);
  }
}

// ---- group norm over 128 per (row,h), in place + affine ------------------
__global__ __launch_bounds__(256)
void gn_kernel(float* __restrict__ Y, const float* __restrict__ w,
               const float* __restrict__ bb) {
  const int wave = threadIdx.x >> 6, lane = threadIdx.x & 63;
  #pragma unroll
  for (int rep = 0; rep < 4; rep++) {
    const int grp = blockIdx.x * 16 + wave * 4 + rep;   // srow*8 + h
    const int h = grp & 7;
    float* yp = Y + (size_t)grp * 128 + lane * 2;
    const float y0 = yp[0], y1 = yp[1];
    const float s = wredf(y0 + y1);
    const float sq = wredf(y0 * y0 + y1 * y1);
    const float mean = s * (1.f / 128.f);
    const float var = fmaxf(sq * (1.f / 128.f) - mean * mean, 0.f);
    const float inv = rsqrtf(var + 1e-5f);
    const int vi = h * 128 + lane * 2;
    yp[0] = (y0 - mean) * inv * w[vi] + bb[vi];
    yp[1] = (y1 - mean) * inv * w[vi + 1] + bb[vi + 1];
  }
}

// ---- final N=1 dot (fp32) ------------------------------------------------
__global__ __launch_bounds__(256)
void head3_kernel(const float* __restrict__ X, const float* __restrict__ w,
                  const float* __restrict__ b3, float* __restrict__ out) {
  const int row = blockIdx.x * 4 + (threadIdx.x >> 6);
  const int lane = threadIdx.x & 63;
  const float* xp = X + (size_t)row * 512 + lane * 8;
  const float* wp = w + lane * 8;
  float s = 0.f;
  #pragma unroll
  for (int j = 0; j < 8; j++) s += xp[j] * wp[j];
  s = wredf(s);
  if (lane == 0) out[row] = s + b3[0];
}

// ---- BMODE1 weight pointer: QKV-mapped B column --------------------------
DEV const float* qkv_bptr(const float* B, const float* B2, const float* B3,
                          int c, int k) {
  if (c < 512)  return B  + ((size_t)(c >> 6) * 512 + k) * 64 + (c & 63);
  if (c < 1024) return B2 + ((size_t)((c - 512) >> 6) * 512 + k) * 64 + ((c - 512) & 63);
  return B3 + ((size_t)((c - 1024) >> 7) * 512 + k) * 128 + ((c - 1024) & 127);
}

// ---- register-blocked fp32 GEMM: C(MxN) = A(MxK) @ B(KxN) + epilogue -----
// 128x128 tile, BK=16, 256 threads, 8x8 microtile (cols split tx*4 / 64+tx*4
// so LDS b-reads are <=2-way bank aliased). A staged transposed in LDS.
// BMODE 0: B natural (KxN).  BMODE 1: QKV weight mapping.
// EPI 0: store    1: silu(acc)*aux     2: acc+aux
//     3: gelu(acc+bias)   4: acc+bias+aux   5: w0*sin(acc+b)+w1*cos(acc+b)
template<int EPI, int BMODE>
__global__ __launch_bounds__(256)
void gemm_f32(const float* __restrict__ A, const float* __restrict__ B,
              const float* __restrict__ B2, const float* __restrict__ B3,
              float* __restrict__ C, int N, int K,
              const float* __restrict__ bias, const float* __restrict__ aux,
              const float* __restrict__ wave2) {
  __shared__ float As[16][132];   // [k][m] transposed
  __shared__ float Bs[16][132];   // [k][n]
  const int tid = threadIdx.x;
  const int tx = tid & 15, ty = tid >> 4;
  const int m0 = blockIdx.y * 128;
  const int n0 = blockIdx.x * 128;

  float acc[8][8];
  #pragma unroll
  for (int i = 0; i < 8; i++)
    #pragma unroll
    for (int j = 0; j < 8; j++) acc[i][j] = 0.f;

  const int am = tid >> 1;             // 0..127 : A row within tile
  const int ak0 = (tid & 1) * 8;       // 0 / 8  : A k sub-offset
  const int bk = tid >> 4;             // 0..15  : B k row
  const int bn = (tid & 15) * 8;       // 0..120 : B col offset
  const float* Aptr = A + (size_t)(m0 + am) * K + ak0;

  for (int kt = 0; kt < K; kt += 16) {
    float a0[8];
    ld4(a0, Aptr + kt);
    ld4(a0 + 4, Aptr + kt + 4);
    float4 b0, b1;
    if constexpr (BMODE == 0) {
      const float* bp = B + (size_t)(kt + bk) * N + n0 + bn;
      b0 = *(const float4*)bp;
      b1 = *(const float4*)(bp + 4);
    } else {
      b0 = *(const float4*)qkv_bptr(B, B2, B3, n0 + bn, kt + bk);
      b1 = *(const float4*)qkv_bptr(B, B2, B3, n0 + bn + 4, kt + bk);
    }
    #pragma unroll
    for (int j = 0; j < 8; j++) As[ak0 + j][am] = a0[j];
    *(float4*)&Bs[bk][bn] = b0;
    *(float4*)&Bs[bk][bn + 4] = b1;
    __syncthreads();
    #pragma unroll
    for (int kk = 0; kk < 16; kk++) {
      float a[8], b[8];
      ld4(a, &As[kk][ty * 8]);
      ld4(a + 4, &As[kk][ty * 8 + 4]);
      ld4(b, &Bs[kk][tx * 4]);
      ld4(b + 4, &Bs[kk][64 + tx * 4]);
      #pragma unroll
      for (int i = 0; i < 8; i++)
        #pragma unroll
        for (int j = 0; j < 8; j++)
          acc[i][j] = fmaf(a[i], b[j], acc[i][j]);
    }
    __syncthreads();
  }

  // epilogue: rows m0+ty*8+i ; col halves n0+tx*4 and n0+64+tx*4
  #pragma unroll
  for (int i = 0; i < 8; i++) {
    const int r = m0 + ty * 8 + i;
    #pragma unroll
    for (int half = 0; half < 2; half++) {
      const int c = n0 + half * 64 + tx * 4;
      const size_t idx = (size_t)r * N + c;
      float o[4];
      #pragma unroll
      for (int j = 0; j < 4; j++) {
        float v = acc[i][half * 4 + j];
        if constexpr (EPI == 0) {
          o[j] = v;
        } else if constexpr (EPI == 1) {
          const float g = v / (1.f + expf(-v));
          o[j] = g * aux[idx + j];
        } else if constexpr (EPI == 2) {
          o[j] = v + aux[idx + j];
        } else if constexpr (EPI == 3) {
          v += bias[c + j];
          o[j] = 0.5f * v * (1.f + erff(v * 0.70710678118654752f));
        } else if constexpr (EPI == 4) {
          o[j] = v + bias[c + j] + aux[idx + j];
        } else if constexpr (EPI == 5) {
          v += bias[c + j];
          o[j] = wave2[0] * sinf(v) + wave2[1] * cosf(v);
        }
      }
      st4(&C[idx], o);
    }
  }
}

// ---- launch --------------------------------------------------------------

extern "C" void kernel_launch(void* const* d_in, const int* in_sizes, int n_in,
                              void* d_out, int out_size, void* d_ws, size_t ws_size,
                              hipStream_t stream) {
  (void)in_sizes; (void)n_in; (void)out_size;
  const float* x    = (const float*)d_in[0];
  const float* t    = (const float*)d_in[1];
  const float* embW = (const float*)d_in[2];
  const float* embB = (const float*)d_in[3];
  const float* ln1w = (const float*)d_in[4];
  const float* ln1b = (const float*)d_in[5];
  const float* ln2w = (const float*)d_in[6];
  const float* ln2b = (const float*)d_in[7];
  const float* WQ   = (const float*)d_in[8];
  const float* WK   = (const float*)d_in[9];
  const float* WV   = (const float*)d_in[10];
  const float* WG   = (const float*)d_in[11];
  const float* WO   = (const float*)d_in[12];
  const float* gnw  = (const float*)d_in[13];
  const float* gnb  = (const float*)d_in[14];
  const float* f1W  = (const float*)d_in[15];
  const float* f1b  = (const float*)d_in[16];
  const float* f2W  = (const float*)d_in[17];
  const float* f2bp = (const float*)d_in[18];
  const float* h1W  = (const float*)d_in[19];
  const float* h1b  = (const float*)d_in[20];
  const float* wvw  = (const float*)d_in[21];
  const float* h2W  = (const float*)d_in[22];
  const float* h2b  = (const float*)d_in[23];
  const float* h3W  = (const float*)d_in[24];
  const float* h3b  = (const float*)d_in[25];

  // ---- choose batch-chunking so fp32 activations fit ws_size ----
  // per-row floats: Xf 512 + Xn 512 + QKV 2048 + Yb 1024 + Yr 512 = 4608
  int NC = 1;
  while (NC < 256) {
    const size_t R = 65536u / NC;
    if (R * 18432 + 4096 <= ws_size) break;
    NC <<= 1;
  }
  const int R = 65536 / NC;   // rows per chunk (multiple of 256)

  float* Xf   = (float*)d_ws;            // R x 512   residual
  float* Xn   = Xf  + (size_t)R * 512;   // R x 512   LN out / H1
  float* QKVb = Xn  + (size_t)R * 512;   // R x 2048  QKV; later GY in first 1024
  float* Yb   = QKVb + (size_t)R * 2048; // R x 1024  Y / mid / H2
  float* Yr   = Yb  + (size_t)R * 1024;  // R x 512   Yr residual branch

  const dim3 blk(256);

  for (int c = 0; c < NC; c++) {
    const size_t off = (size_t)c * R;
    embed_kernel<<<dim3(R / 4), blk, 0, stream>>>(x + off, t + off, embW, embB, Xf);

    for (int l = 0; l < 4; l++) {
      ln_kernel<<<dim3(R / 4), blk, 0, stream>>>(Xf, ln1w + l * 512, ln1b + l * 512, Xn);
      // QKV = Xn @ [WQ|WK|WV][l]   (N=2048, K=512, head-mapped B)
      gemm_f32<0, 1><<<dim3(16, R / 128), blk, 0, stream>>>(
          Xn, WQ + (size_t)l * 262144, WK + (size_t)l * 262144,
          WV + (size_t)l * 524288, QKVb, 2048, 512, nullptr, nullptr, nullptr);
      xpos_kernel<<<dim3(R), blk, 0, stream>>>(QKVb);
      attn_tiled<<<dim3(R / 64, 8), blk, 0, stream>>>(QKVb, Yb);
      gn_kernel<<<dim3(R / 2), blk, 0, stream>>>(Yb, gnw + l * 1024, gnb + l * 1024);
      // GY = silu(Xn @ WG[l]) * Y   -> first R*1024 of QKVb (QKV dead)
      gemm_f32<1, 0><<<dim3(8, R / 128), blk, 0, stream>>>(
          Xn, WG + (size_t)l * 524288, nullptr, nullptr,
          QKVb, 1024, 512, nullptr, Yb, nullptr);
      // Yr = GY @ WO[l] + X
      gemm_f32<2, 0><<<dim3(4, R / 128), blk, 0, stream>>>(
          QKVb, WO + (size_t)l * 524288, nullptr, nullptr,
          Yr, 512, 1024, nullptr, Xf, nullptr);
      ln_kernel<<<dim3(R / 4), blk, 0, stream>>>(Yr, ln2w + l * 512, ln2b + l * 512, Xn);
      // mid = gelu(Xn @ f1[l] + b1)  -> Yb (Y dead)
      gemm_f32<3, 0><<<dim3(1, R / 128), blk, 0, stream>>>(
          Xn, f1W + (size_t)l * 65536, nullptr, nullptr,
          Yb, 128, 512, f1b + l * 128, nullptr, nullptr);
      // X = mid @ f2[l] + b2 + Yr
      gemm_f32<4, 0><<<dim3(4, R / 128), blk, 0, stream>>>(
          Yb, f2W + (size_t)l * 65536, nullptr, nullptr,
          Xf, 512, 128, f2bp + l * 512, Yr, nullptr);
    }

    // head
    gemm_f32<5, 0><<<dim3(4, R / 128), blk, 0, stream>>>(
        Xf, h1W, nullptr, nullptr, Xn, 512, 512, h1b, nullptr, wvw);
    gemm_f32<5, 0><<<dim3(4, R / 128), blk, 0, stream>>>(
        Xn, h2W, nullptr, nullptr, Yb, 512, 512, h2b, nullptr, wvw + 2);
    head3_kernel<<<dim3(R / 4), blk, 0, stream>>>(
        Yb, h3W, h3b, (float*)d_out + off);
  }
}

// Round 2
// 17965.703 us; speedup vs baseline: 4.8826x; 1.4334x over previous
//
#include <hip/hip_runtime.h>
#include <cstdint>
#include <cstddef>

#define DEV static __device__ __forceinline__

typedef short bf16x8 __attribute__((ext_vector_type(8)));
typedef float f32x4 __attribute__((ext_vector_type(4)));

DEV float wredf(float v) {
  v += __shfl_xor(v, 32, 64); v += __shfl_xor(v, 16, 64);
  v += __shfl_xor(v, 8, 64);  v += __shfl_xor(v, 4, 64);
  v += __shfl_xor(v, 2, 64);  v += __shfl_xor(v, 1, 64);
  return v;
}

DEV void ld4(float* d, const float* p) {
  float4 t = *(const float4*)p;
  d[0] = t.x; d[1] = t.y; d[2] = t.z; d[3] = t.w;
}
DEV void st4(float* p, const float* s) {
  *(float4*)p = make_float4(s[0], s[1], s[2], s[3]);
}

// round-to-nearest-even fp32 -> bf16 bits
DEV unsigned int bfh16(float v) {
  unsigned int u = __float_as_uint(v);
  return (u + 0x7FFFu + ((u >> 16) & 1u)) >> 16;
}
// split pair (a,b) -> packed hi-word / lo-word (2x bf16 each)
DEV uint2 splitpk(float a, float b) {
  unsigned int ha = bfh16(a), hb = bfh16(b);
  float la = a - __uint_as_float(ha << 16);
  float lb = b - __uint_as_float(hb << 16);
  return make_uint2(ha | (hb << 16), bfh16(la) | (bfh16(lb) << 16));
}

// ---- embed: src = [x,t] @ emb_W + emb_b  (fp32) --------------------------
__global__ __launch_bounds__(256)
void embed_kernel(const float* __restrict__ x, const float* __restrict__ t,
                  const float* __restrict__ W, const float* __restrict__ eb,
                  float* __restrict__ X) {
  const int gid = blockIdx.x * 256 + threadIdx.x;  // R*64
  const int row = gid >> 6, d = (gid & 63) * 8;
  const float xv = x[row], tv = t[row];
  #pragma unroll
  for (int j = 0; j < 8; j++)
    X[(size_t)row * 512 + d + j] =
        xv * W[d + j] + tv * W[512 + d + j] + eb[d + j];
}

// ---- layernorm row=512, fp32 -> fp32, one wave per row -------------------
__global__ __launch_bounds__(256)
void ln_kernel(const float* __restrict__ X, const float* __restrict__ w,
               const float* __restrict__ bb, float* __restrict__ out) {
  const int row = blockIdx.x * 4 + (threadIdx.x >> 6);
  const int lane = threadIdx.x & 63;
  const float* xp = X + (size_t)row * 512 + lane * 8;
  float4 a0 = *(const float4*)xp;
  float4 a1 = *(const float4*)(xp + 4);
  float v[8] = {a0.x, a0.y, a0.z, a0.w, a1.x, a1.y, a1.z, a1.w};
  float s = 0.f, sq = 0.f;
  #pragma unroll
  for (int j = 0; j < 8; j++) { s += v[j]; sq += v[j] * v[j]; }
  s = wredf(s); sq = wredf(sq);
  const float mean = s * (1.f / 512.f);
  const float var = fmaxf(sq * (1.f / 512.f) - mean * mean, 0.f);
  const float inv = rsqrtf(var + 1e-5f);
  const float* wp = w + lane * 8;
  const float* bp = bb + lane * 8;
  float* op = out + (size_t)row * 512 + lane * 8;
  #pragma unroll
  for (int j = 0; j < 8; j++)
    op[j] = (v[j] - mean) * inv * wp[j] + bp[j];
}

// ---- xpos rotation + folded retention decay on Q,K -----------------------
__global__ __launch_bounds__(256)
void xpos_kernel(float* __restrict__ QKV) {
  const int gid = blockIdx.x * 256 + threadIdx.x;  // R*256
  const int row = gid >> 8, r = gid & 255;
  const int h = r >> 5, i = r & 31;
  const int s = row & 255;
  const float sv = (2.0f * i + 0.4f * 64.0f) / (1.4f * 64.0f);
  const float sc = powf(sv, (float)s / 512.0f);
  const float isc = 1.0f / sc;
  const float invf = powf(10000.0f, -((float)i) / 32.0f);
  const float ang = (float)s * invf;
  const float sn = sinf(ang), cs = cosf(ang);
  const float l32 = logf(1.0f / 32.0f), l512 = logf(1.0f / 512.0f);
  const float gamma = 1.0f - expf(l32 + (float)h * (l512 - l32) / 7.0f);
  const float gq = powf(gamma, (float)s);
  const float gk = 1.0f / gq;
  const size_t base = (size_t)row * 2048 + h * 64 + 2 * i;
  const float q0 = QKV[base], q1 = QKV[base + 1];
  const float k0 = QKV[base + 512], k1 = QKV[base + 513];
  const float cq = cs * sc * gq, sq_ = sn * sc * gq;
  const float ck = cs * isc * gk, sk = sn * isc * gk;
  QKV[base]       = q0 * cq - q1 * sq_;
  QKV[base + 1]   = q1 * cq + q0 * sq_;
  QKV[base + 512] = k0 * ck - k1 * sk;
  QKV[base + 513] = k1 * ck + k0 * sk;
}

// ---- tiled causal retention attention (fp32) -----------------------------
__global__ __launch_bounds__(256)
void attn_tiled(const float* __restrict__ QKV, float* __restrict__ Y) {
  __shared__ float Qs[64][68];   // [e][s]
  __shared__ float Ks[64][68];   // [e][m]
  __shared__ float At[64][68];   // [m][s]
  const int h = blockIdx.y;
  const int r0 = blockIdx.x * 64;       // chunk-local first row
  const int b = r0 >> 8;
  const int s0 = r0 & 255;
  const int st = s0 >> 6;               // diagonal m-tile index
  const int tid = threadIdx.x;
  const int ty = tid >> 4, tx = tid & 15;

  {  // stage Q transposed
    const int rr = tid >> 2, e0 = (tid & 3) * 16;
    const float* qp = QKV + (size_t)(r0 + rr) * 2048 + h * 64 + e0;
    #pragma unroll
    for (int j = 0; j < 16; j++) Qs[e0 + j][rr] = qp[j];
  }

  float acc2[4][8];
  #pragma unroll
  for (int i = 0; i < 4; i++)
    #pragma unroll
    for (int j = 0; j < 8; j++) acc2[i][j] = 0.f;

  for (int mt = 0; mt <= st; mt++) {
    const int m0 = mt * 64;
    {  // stage K tile transposed
      const int rr = tid >> 2, e0 = (tid & 3) * 16;
      const float* kp = QKV + (size_t)(b * 256 + m0 + rr) * 2048 + 512 + h * 64 + e0;
      #pragma unroll
      for (int j = 0; j < 16; j++) Ks[e0 + j][rr] = kp[j];
    }
    __syncthreads();
    float a1[4][4];
    #pragma unroll
    for (int i = 0; i < 4; i++)
      #pragma unroll
      for (int j = 0; j < 4; j++) a1[i][j] = 0.f;
    #pragma unroll 4
    for (int e = 0; e < 64; e++) {
      float qa[4], kb[4];
      ld4(qa, &Qs[e][ty * 4]);
      ld4(kb, &Ks[e][tx * 4]);
      #pragma unroll
      for (int i = 0; i < 4; i++)
        #pragma unroll
        for (int j = 0; j < 4; j++)
          a1[i][j] = fmaf(qa[i], kb[j], a1[i][j]);
    }
    #pragma unroll
    for (int i = 0; i < 4; i++)
      #pragma unroll
      for (int j = 0; j < 4; j++) {
        float v = a1[i][j];
        if (mt == st && (m0 + tx * 4 + j) > (s0 + ty * 4 + i)) v = 0.f;
        At[tx * 4 + j][ty * 4 + i] = v;
      }
    __syncthreads();
    const float* vp = QKV + (size_t)(b * 256 + m0) * 2048 + 1024 + h * 128 + tx * 8;
    #pragma unroll 4
    for (int m = 0; m < 64; m++) {
      float av[4], vv[8];
      ld4(av, &At[m][ty * 4]);
      ld4(vv, vp);
      ld4(vv + 4, vp + 4);
      vp += 2048;
      #pragma unroll
      for (int i = 0; i < 4; i++)
        #pragma unroll
        for (int j = 0; j < 8; j++)
          acc2[i][j] = fmaf(av[i], vv[j], acc2[i][j]);
    }
    __syncthreads();
  }
  #pragma unroll
  for (int i = 0; i < 4; i++) {
    float* yp = Y + (size_t)(r0 + ty * 4 + i) * 1024 + h * 128 + tx * 8;
    st4(yp, &acc2[i][0]);
    st4(yp + 4, &acc2[i][4]);
  }
}

// ---- group norm over 128 per (row,h), in place + affine ------------------
__global__ __launch_bounds__(256)
void gn_kernel(float* __restrict__ Y, const float* __restrict__ w,
               const float* __restrict__ bb) {
  const int wave = threadIdx.x >> 6, lane = threadIdx.x & 63;
  #pragma unroll
  for (int rep = 0; rep < 4; rep++) {
    const int grp = blockIdx.x * 16 + wave * 4 + rep;   // srow*8 + h
    const int h = grp & 7;
    float* yp = Y + (size_t)grp * 128 + lane * 2;
    const float y0 = yp[0], y1 = yp[1];
    const float s = wredf(y0 + y1);
    const float sq = wredf(y0 * y0 + y1 * y1);
    const float mean = s * (1.f / 128.f);
    const float var = fmaxf(sq * (1.f / 128.f) - mean * mean, 0.f);
    const float inv = rsqrtf(var + 1e-5f);
    const int vi = h * 128 + lane * 2;
    yp[0] = (y0 - mean) * inv * w[vi] + bb[vi];
    yp[1] = (y1 - mean) * inv * w[vi + 1] + bb[vi + 1];
  }
}

// ---- final N=1 dot (fp32) ------------------------------------------------
__global__ __launch_bounds__(256)
void head3_kernel(const float* __restrict__ X, const float* __restrict__ w,
                  const float* __restrict__ b3, float* __restrict__ out) {
  const int row = blockIdx.x * 4 + (threadIdx.x >> 6);
  const int lane = threadIdx.x & 63;
  const float* xp = X + (size_t)row * 512 + lane * 8;
  const float* wp = w + lane * 8;
  float s = 0.f;
  #pragma unroll
  for (int j = 0; j < 8; j++) s += xp[j] * wp[j];
  s = wredf(s);
  if (lane == 0) out[row] = s + b3[0];
}

// ---- weight pre-pack: W[K][N] (fp32) -> Bt_hi/Bt_lo [N][K] (bf16) --------
__global__ __launch_bounds__(256)
void pack_plain(const float* __restrict__ W, unsigned short* __restrict__ hi,
                unsigned short* __restrict__ lo, int N, int kshift) {
  const int idx = blockIdx.x * 256 + threadIdx.x;   // n*K + k
  const int K = 1 << kshift;
  const int n = idx >> kshift, k = idx & (K - 1);
  const float v = W[(size_t)k * N + n];
  const unsigned int h = bfh16(v);
  const float l = v - __uint_as_float(h << 16);
  hi[idx] = (unsigned short)h;
  lo[idx] = (unsigned short)bfh16(l);
}

// QKV head-interleaved mapping: col c<512 -> WQ(h,k,e), <1024 -> WK, else WV
__global__ __launch_bounds__(256)
void pack_qkv(const float* __restrict__ WQ, const float* __restrict__ WK,
              const float* __restrict__ WV, unsigned short* __restrict__ hi,
              unsigned short* __restrict__ lo) {
  const int idx = blockIdx.x * 256 + threadIdx.x;   // c*512 + k
  const int c = idx >> 9, k = idx & 511;
  float v;
  if (c < 512)
    v = WQ[((size_t)(c >> 6) * 512 + k) * 64 + (c & 63)];
  else if (c < 1024)
    v = WK[((size_t)((c - 512) >> 6) * 512 + k) * 64 + ((c - 512) & 63)];
  else
    v = WV[((size_t)((c - 1024) >> 7) * 512 + k) * 128 + ((c - 1024) & 127)];
  const unsigned int h = bfh16(v);
  const float l = v - __uint_as_float(h << 16);
  hi[idx] = (unsigned short)h;
  lo[idx] = (unsigned short)bfh16(l);
}

// ---- bf16x3 MFMA GEMM: C(MxN) = A(MxK) @ B(KxN) + epilogue ---------------
// A fp32 [M][K] (split to hi/lo bf16 in-kernel), B pre-packed [N][K] hi/lo.
// 128x128 tile, BK=32, 4 waves (2x2 of 64x64), 4x4 frags of 16x16x32 MFMA.
// acc += ah*bh + ah*bl + al*bh   (al*bl term ~2^-18, dropped)
// LDS rows padded to 40 shorts (80 B) -> <=2-way bank conflicts on b128.
// EPI 0: store    1: silu(acc)*aux     2: acc+aux
//     3: gelu(acc+bias)   4: acc+bias+aux   5: w0*sin(acc+b)+w1*cos(acc+b)
template<int EPI>
__global__ __launch_bounds__(256, 2)
void gemm_mfma(const float* __restrict__ A, const unsigned short* __restrict__ Bh,
               const unsigned short* __restrict__ Bl, float* __restrict__ C,
               const int N, const int K,
               const float* __restrict__ bias, const float* __restrict__ aux,
               const float* __restrict__ wave2) {
  __shared__ __align__(16) unsigned short Ah[128][40];
  __shared__ __align__(16) unsigned short Al[128][40];
  __shared__ __align__(16) unsigned short Bhs[128][40];
  __shared__ __align__(16) unsigned short Bls[128][40];
  const int tid = threadIdx.x;
  const int lane = tid & 63;
  const int wave = tid >> 6;
  const int wr = (wave >> 1) * 64, wc = (wave & 1) * 64;
  const int m0 = blockIdx.y * 128, n0 = blockIdx.x * 128;

  // staging assignment: A: thread -> (row, 16-float k-chunk); B: row + hi/lo
  const int ar = tid >> 1, ak = (tid & 1) * 16;
  const float* Ap = A + (size_t)(m0 + ar) * K + ak;
  const int bu = tid & 127;
  const unsigned short* Bp = ((tid >> 7) ? Bl : Bh) + (size_t)(n0 + bu) * K;
  unsigned short* Bw = ((tid >> 7) ? &Bls[0][0] : &Bhs[0][0]) + bu * 40;

  const int fm = lane & 15;
  const int fkb = (lane >> 4) * 16;   // byte offset of this lane's k-slice

  f32x4 acc[4][4];
  #pragma unroll
  for (int i = 0; i < 4; i++)
    #pragma unroll
    for (int j = 0; j < 4; j++)
      acc[i][j] = (f32x4){0.f, 0.f, 0.f, 0.f};

  float a_reg[16];
  int4 b_reg[4];
  ld4(a_reg, Ap);       ld4(a_reg + 4, Ap + 4);
  ld4(a_reg + 8, Ap + 8); ld4(a_reg + 12, Ap + 12);
  #pragma unroll
  for (int i = 0; i < 4; i++) b_reg[i] = *(const int4*)(Bp + i * 8);

  for (int kt = 0; kt < K; kt += 32) {
    {  // split + write A, write B
      uint2 q0 = splitpk(a_reg[0], a_reg[1]);
      uint2 q1 = splitpk(a_reg[2], a_reg[3]);
      uint2 q2 = splitpk(a_reg[4], a_reg[5]);
      uint2 q3 = splitpk(a_reg[6], a_reg[7]);
      uint2 q4 = splitpk(a_reg[8], a_reg[9]);
      uint2 q5 = splitpk(a_reg[10], a_reg[11]);
      uint2 q6 = splitpk(a_reg[12], a_reg[13]);
      uint2 q7 = splitpk(a_reg[14], a_reg[15]);
      *(int4*)&Ah[ar][ak]     = make_int4(q0.x, q1.x, q2.x, q3.x);
      *(int4*)&Ah[ar][ak + 8] = make_int4(q4.x, q5.x, q6.x, q7.x);
      *(int4*)&Al[ar][ak]     = make_int4(q0.y, q1.y, q2.y, q3.y);
      *(int4*)&Al[ar][ak + 8] = make_int4(q4.y, q5.y, q6.y, q7.y);
      *(int4*)&Bw[0]  = b_reg[0];
      *(int4*)&Bw[8]  = b_reg[1];
      *(int4*)&Bw[16] = b_reg[2];
      *(int4*)&Bw[24] = b_reg[3];
    }
    __syncthreads();
    if (kt + 32 < K) {  // prefetch next tile into regs (spans MFMA phase)
      const float* ap = Ap + kt + 32;
      ld4(a_reg, ap);        ld4(a_reg + 4, ap + 4);
      ld4(a_reg + 8, ap + 8); ld4(a_reg + 12, ap + 12);
      const unsigned short* bp = Bp + kt + 32;
      #pragma unroll
      for (int i = 0; i < 4; i++) b_reg[i] = *(const int4*)(bp + i * 8);
    }
    bf16x8 avh[4], avl[4];
    #pragma unroll
    for (int mf = 0; mf < 4; mf++) {
      const int m = wr + mf * 16 + fm;
      avh[mf] = *(const bf16x8*)((const char*)&Ah[m][0] + fkb);
      avl[mf] = *(const bf16x8*)((const char*)&Al[m][0] + fkb);
    }
    #pragma unroll
    for (int nf = 0; nf < 4; nf++) {
      const int n = wc + nf * 16 + fm;
      bf16x8 bh = *(const bf16x8*)((const char*)&Bhs[n][0] + fkb);
      bf16x8 bl = *(const bf16x8*)((const char*)&Bls[n][0] + fkb);
      #pragma unroll
      for (int mf = 0; mf < 4; mf++) {
        acc[mf][nf] = __builtin_amdgcn_mfma_f32_16x16x32_bf16(avh[mf], bh, acc[mf][nf], 0, 0, 0);
        acc[mf][nf] = __builtin_amdgcn_mfma_f32_16x16x32_bf16(avl[mf], bh, acc[mf][nf], 0, 0, 0);
        acc[mf][nf] = __builtin_amdgcn_mfma_f32_16x16x32_bf16(avh[mf], bl, acc[mf][nf], 0, 0, 0);
      }
    }
    __syncthreads();
  }

  // epilogue: D frag: col = lane&15, row = (lane>>4)*4 + r
  const int r0 = m0 + wr + (lane >> 4) * 4;
  const int c0 = n0 + wc + fm;
  #pragma unroll
  for (int mf = 0; mf < 4; mf++) {
    #pragma unroll
    for (int nf = 0; nf < 4; nf++) {
      const int col = c0 + nf * 16;
      #pragma unroll
      for (int r = 0; r < 4; r++) {
        const int row = r0 + mf * 16 + r;
        const size_t idx = (size_t)row * N + col;
        float v = acc[mf][nf][r];
        float o;
        if constexpr (EPI == 0) {
          o = v;
        } else if constexpr (EPI == 1) {
          const float g = v / (1.f + expf(-v));
          o = g * aux[idx];
        } else if constexpr (EPI == 2) {
          o = v + aux[idx];
        } else if constexpr (EPI == 3) {
          v += bias[col];
          o = 0.5f * v * (1.f + erff(v * 0.70710678118654752f));
        } else if constexpr (EPI == 4) {
          o = v + bias[col] + aux[idx];
        } else {
          v += bias[col];
          o = wave2[0] * sinf(v) + wave2[1] * cosf(v);
        }
        C[idx] = o;
      }
    }
  }
}

// ---- launch --------------------------------------------------------------

extern "C" void kernel_launch(void* const* d_in, const int* in_sizes, int n_in,
                              void* d_out, int out_size, void* d_ws, size_t ws_size,
                              hipStream_t stream) {
  (void)in_sizes; (void)n_in; (void)out_size;
  const float* x    = (const float*)d_in[0];
  const float* t    = (const float*)d_in[1];
  const float* embW = (const float*)d_in[2];
  const float* embB = (const float*)d_in[3];
  const float* ln1w = (const float*)d_in[4];
  const float* ln1b = (const float*)d_in[5];
  const float* ln2w = (const float*)d_in[6];
  const float* ln2b = (const float*)d_in[7];
  const float* WQ   = (const float*)d_in[8];
  const float* WK   = (const float*)d_in[9];
  const float* WV   = (const float*)d_in[10];
  const float* WG   = (const float*)d_in[11];
  const float* WO   = (const float*)d_in[12];
  const float* gnw  = (const float*)d_in[13];
  const float* gnb  = (const float*)d_in[14];
  const float* f1W  = (const float*)d_in[15];
  const float* f1b  = (const float*)d_in[16];
  const float* f2W  = (const float*)d_in[17];
  const float* f2bp = (const float*)d_in[18];
  const float* h1W  = (const float*)d_in[19];
  const float* h1b  = (const float*)d_in[20];
  const float* wvw  = (const float*)d_in[21];
  const float* h2W  = (const float*)d_in[22];
  const float* h2b  = (const float*)d_in[23];
  const float* h3W  = (const float*)d_in[24];
  const float* h3b  = (const float*)d_in[25];

  // ---- packed-weight area (bf16 hi/lo, [N][K]) at start of ws ----
  typedef unsigned short u16;
  u16* P = (u16*)d_ws;
  const size_t SQKV = 2048 * 512, SWG = 1024 * 512, SWO = 512 * 1024;
  const size_t SF1 = 128 * 512, SF2 = 512 * 128;
  const size_t PERL = 2 * (SQKV + SWG + SWO + SF1 + SF2);
  const size_t HOFF = 4 * PERL;                 // heads after layers
  const size_t PACK_BYTES = (HOFF + 4 * 512 * 512) * 2;  // = 37748736

  u16* h1h = P + HOFF;
  u16* h1l = h1h + 512 * 512;
  u16* h2h = h1l + 512 * 512;
  u16* h2l = h2h + 512 * 512;

  const dim3 blk(256);

  // pack all weights once
  for (int l = 0; l < 4; l++) {
    u16* qkvh = P + l * PERL;
    u16* qkvl = qkvh + SQKV;
    u16* wgh  = qkvl + SQKV;
    u16* wgl  = wgh + SWG;
    u16* woh  = wgl + SWG;
    u16* wol  = woh + SWO;
    u16* f1h  = wol + SWO;
    u16* f1l  = f1h + SF1;
    u16* f2h  = f1l + SF1;
    u16* f2l  = f2h + SF2;
    pack_qkv<<<dim3(SQKV / 256), blk, 0, stream>>>(
        WQ + (size_t)l * 262144, WK + (size_t)l * 262144,
        WV + (size_t)l * 524288, qkvh, qkvl);
    pack_plain<<<dim3(SWG / 256), blk, 0, stream>>>(WG + (size_t)l * 524288, wgh, wgl, 1024, 9);
    pack_plain<<<dim3(SWO / 256), blk, 0, stream>>>(WO + (size_t)l * 524288, woh, wol, 512, 10);
    pack_plain<<<dim3(SF1 / 256), blk, 0, stream>>>(f1W + (size_t)l * 65536, f1h, f1l, 128, 9);
    pack_plain<<<dim3(SF2 / 256), blk, 0, stream>>>(f2W + (size_t)l * 65536, f2h, f2l, 512, 7);
  }
  pack_plain<<<dim3(1024), blk, 0, stream>>>(h1W, h1h, h1l, 512, 9);
  pack_plain<<<dim3(1024), blk, 0, stream>>>(h2W, h2h, h2l, 512, 9);

  // ---- batch-chunking so fp32 activations fit after the pack area ----
  int NC = 1;
  while (NC < 256) {
    const size_t R = 65536u / NC;
    if (PACK_BYTES + R * 18432 + 4096 <= ws_size) break;
    NC <<= 1;
  }
  const int R = 65536 / NC;   // rows per chunk (multiple of 256)

  float* Xf   = (float*)((char*)d_ws + PACK_BYTES);  // R x 512 residual
  float* Xn   = Xf  + (size_t)R * 512;   // R x 512   LN out / H1
  float* QKVb = Xn  + (size_t)R * 512;   // R x 2048  QKV; later GY in first 1024
  float* Yb   = QKVb + (size_t)R * 2048; // R x 1024  Y / mid / H2
  float* Yr   = Yb  + (size_t)R * 1024;  // R x 512   Yr residual branch

  for (int c = 0; c < NC; c++) {
    const size_t off = (size_t)c * R;
    embed_kernel<<<dim3(R / 4), blk, 0, stream>>>(x + off, t + off, embW, embB, Xf);

    for (int l = 0; l < 4; l++) {
      u16* qkvh = P + l * PERL;
      u16* qkvl = qkvh + SQKV;
      u16* wgh  = qkvl + SQKV;
      u16* wgl  = wgh + SWG;
      u16* woh  = wgl + SWG;
      u16* wol  = woh + SWO;
      u16* f1h  = wol + SWO;
      u16* f1l  = f1h + SF1;
      u16* f2h  = f1l + SF1;
      u16* f2l  = f2h + SF2;

      ln_kernel<<<dim3(R / 4), blk, 0, stream>>>(Xf, ln1w + l * 512, ln1b + l * 512, Xn);
      // QKV = Xn @ [WQ|WK|WV][l]
      gemm_mfma<0><<<dim3(16, R / 128), blk, 0, stream>>>(
          Xn, qkvh, qkvl, QKVb, 2048, 512, nullptr, nullptr, nullptr);
      xpos_kernel<<<dim3(R), blk, 0, stream>>>(QKVb);
      attn_tiled<<<dim3(R / 64, 8), blk, 0, stream>>>(QKVb, Yb);
      gn_kernel<<<dim3(R / 2), blk, 0, stream>>>(Yb, gnw + l * 1024, gnb + l * 1024);
      // GY = silu(Xn @ WG[l]) * Y   -> first R*1024 of QKVb (QKV dead)
      gemm_mfma<1><<<dim3(8, R / 128), blk, 0, stream>>>(
          Xn, wgh, wgl, QKVb, 1024, 512, nullptr, Yb, nullptr);
      // Yr = GY @ WO[l] + X
      gemm_mfma<2><<<dim3(4, R / 128), blk, 0, stream>>>(
          QKVb, woh, wol, Yr, 512, 1024, nullptr, Xf, nullptr);
      ln_kernel<<<dim3(R / 4), blk, 0, stream>>>(Yr, ln2w + l * 512, ln2b + l * 512, Xn);
      // mid = gelu(Xn @ f1[l] + b1)  -> Yb
      gemm_mfma<3><<<dim3(1, R / 128), blk, 0, stream>>>(
          Xn, f1h, f1l, Yb, 128, 512, f1b + l * 128, nullptr, nullptr);
      // X = mid @ f2[l] + b2 + Yr
      gemm_mfma<4><<<dim3(4, R / 128), blk, 0, stream>>>(
          Yb, f2h, f2l, Xf, 512, 128, f2bp + l * 512, Yr, nullptr);
    }

    // head
    gemm_mfma<5><<<dim3(4, R / 128), blk, 0, stream>>>(
        Xf, h1h, h1l, Xn, 512, 512, h1b, nullptr, wvw);
    gemm_mfma<5><<<dim3(4, R / 128), blk, 0, stream>>>(
        Xn, h2h, h2l, Yb, 512, 512, h2b, nullptr, wvw + 2);
    head3_kernel<<<dim3(R / 4), blk, 0, stream>>>(
        Yb, h3W, h3b, (float*)d_out + off);
  }
}